// Round 9
// baseline (165.200 us; speedup 1.0000x reference)
//
#include <hip/hip_runtime.h>

#define S_LEN 2048
#define D_DIM 64
#define BH 32
#define NN ((size_t)131072)  // shorts per bh per ws buffer (2048*64)

typedef short bf16x8 __attribute__((ext_vector_type(8)));
typedef float f32x16 __attribute__((ext_vector_type(16)));
typedef unsigned int u32x4 __attribute__((ext_vector_type(4)));

static __device__ __forceinline__ unsigned short f2bf(float x) {
  unsigned int u = __float_as_uint(x);
  u += 0x7fffu + ((u >> 16) & 1u);
  return (unsigned short)(u >> 16);
}
static __device__ __forceinline__ float bf2f(unsigned short h) {
  return __uint_as_float(((unsigned int)h) << 16);
}
static __device__ __forceinline__ void gll16(const void* g, void* l) {
  __builtin_amdgcn_global_load_lds((const __attribute__((address_space(1))) void*)g,
                                   (__attribute__((address_space(3))) void*)l, 16, 0, 0);
}

// Fused pre-pass, barrier-free / LDS-free. One thread = one 16B fragment unit.
__global__ __launch_bounds__(256) void pack_all(
    const float* __restrict__ kin, const float* __restrict__ vin,
    unsigned short* __restrict__ Kh, unsigned short* __restrict__ Kl,
    unsigned short* __restrict__ Vh) {
  const int gid = blockIdx.x * 256 + threadIdx.x;
  if (gid < 524288) {  // ---- K: 32 bh x 8 u x 2048 t ----
    const int bh = gid >> 14, rem = gid & 16383;
    const int u = rem >> 11, t = rem & 2047;
    const float* src = kin + (size_t)bh * 131072 + (size_t)(u * 8) * 2048 + t;
    float x[8];
#pragma unroll
    for (int j = 0; j < 8; ++j) x[j] = src[j * 2048];
    u32x4 hv, lv;
#pragma unroll
    for (int p = 0; p < 4; ++p) {
      unsigned int pk;
      asm("v_cvt_pk_bf16_f32 %0, %1, %2" : "=v"(pk) : "v"(x[2 * p]), "v"(x[2 * p + 1]));
      float l0 = x[2 * p] - __uint_as_float(pk << 16);
      float l1 = x[2 * p + 1] - __uint_as_float(pk & 0xffff0000u);
      unsigned int pl;
      asm("v_cvt_pk_bf16_f32 %0, %1, %2" : "=v"(pl) : "v"(l0), "v"(l1));
      hv[p] = pk;
      lv[p] = pl;
    }
    const size_t o = (size_t)bh * NN + (size_t)(u * 2048 + t) * 8;
    *(u32x4*)(Kh + o) = hv;
    *(u32x4*)(Kl + o) = lv;
  } else {  // ---- V: 32 bh x 256 thi x 64 d ----
    const int g2 = gid - 524288;
    const int bh = g2 >> 14, rem = g2 & 16383;
    const int thi = rem >> 6, d = rem & 63;
    const int tr = thi >> 3, u = thi & 7;
    const float* src = vin + (size_t)bh * 131072 + d;
    float x[8];
#pragma unroll
    for (int j = 0; j < 8; ++j) {
      int t = tr * 64 + (u >> 1) * 16 + (u & 1) * 4 + (j & 3) + 8 * (j >> 2);
      x[j] = src[(size_t)t * 64];
    }
    u32x4 hv;
#pragma unroll
    for (int p = 0; p < 4; ++p) {
      unsigned int pk;
      asm("v_cvt_pk_bf16_f32 %0, %1, %2" : "=v"(pk) : "v"(x[2 * p]), "v"(x[2 * p + 1]));
      hv[p] = pk;
    }
    *(u32x4*)(Vh + (size_t)bh * NN + (size_t)(thi * 64 + d) * 8) = hv;
  }
}

// Fused exp-attention. 512 thr = 8 waves = 4 q-tiles x 2 key-halves (split-K).
// Swapped-QK^T 32x32x16, in-register P, hi/lo bf16 QK, bf16 V.
// Fragment-linear LDS (0 conflicts). 3-buffer DMA pipeline, stage 2 tiles ahead,
// counted s_waitcnt vmcnt(3) + raw s_barrier per iter (never drain in main loop).
__global__ __launch_bounds__(512, 4) void attn_fused(
    const float* __restrict__ q, const unsigned short* __restrict__ Khg,
    const unsigned short* __restrict__ Klg, const unsigned short* __restrict__ Vhg,
    float* __restrict__ out) {
  __shared__ __align__(16) unsigned short smem[3][12288];  // 3 x 24KB: [Kh 8K][Kl 8K][Vh 8K]

  const int bid = blockIdx.x;
  const int swz = (bid & 7) * 64 + (bid >> 3);  // XCD-contiguous
  const int bh = swz >> 4;
  const int qt = swz & 15;
  const int tid = threadIdx.x;
  const int w = tid >> 6;
  const int lane = tid & 63;
  const int l31 = lane & 31;
  const int h = lane >> 5;
  const int qtile = w >> 1;   // 0..3
  const int kh2 = w & 1;      // key-half 0/1

  // ---- Q B-fragments: col(q)=l31, k(d)=ks*16+h*8+j ----
  bf16x8 qh[4], ql[4];
  {
    const float* qb = q + ((size_t)bh * S_LEN + qt * 128 + qtile * 32 + l31) * 64;
#pragma unroll
    for (int ks = 0; ks < 4; ++ks) {
      const float* p = qb + ks * 16 + h * 8;
      float4 x0 = *(const float4*)p;
      float4 x1 = *(const float4*)(p + 4);
      float xs[8] = {x0.x, x0.y, x0.z, x0.w, x1.x, x1.y, x1.z, x1.w};
      bf16x8 hh, ll;
#pragma unroll
      for (int j = 0; j < 8; ++j) {
        unsigned short hb = f2bf(xs[j]);
        hh[j] = (short)hb;
        ll[j] = (short)f2bf(xs[j] - bf2f(hb));
      }
      qh[ks] = hh; ql[ks] = ll;
    }
  }

  // ---- staging: 24 chunks of 1KB per tile, 3 per wave ----
  const unsigned short* srcp[3];
  int stp[3], ldso[3];
#pragma unroll
  for (int i = 0; i < 3; ++i) {
    int g = w * 3 + i;
    int c = g & 7, typ = g >> 3;  // 0:Kh 1:Kl 2:Vh
    if (typ < 2) {
      size_t off = ((size_t)((c >> 1) * 2 + h) * 2048 + (c & 1) * 32 + l31) * 8;
      srcp[i] = (typ == 0 ? Khg : Klg) + (size_t)bh * NN + off;
      stp[i] = 512;                    // +64 keys per tile
      ldso[i] = typ * 4096 + c * 512;  // shorts
    } else {
      size_t off = ((size_t)((c >> 1) * 2 + h) * 64 + (c & 1) * 32 + l31) * 8;
      srcp[i] = Vhg + (size_t)bh * NN + off;
      stp[i] = 4096;                   // +8 t-octets per tile
      ldso[i] = 8192 + c * 512;
    }
  }
  auto stage = [&](int buf, int tile) {
#pragma unroll
    for (int i = 0; i < 3; ++i)
      gll16(srcp[i] + (size_t)tile * stp[i], &smem[buf][ldso[i]]);
  };

  f32x16 o2[2] = {};
  float lsum = 0.f;
  const char* lp = (const char*)&smem[0][0] + lane * 16;

  auto compute = [&](int bufc) {
    const char* B = lp + bufc * 24576;
    // ---- QK^T (A=K rows of this key-half, B=Q) ----
    f32x16 acc = {};
    __builtin_amdgcn_s_setprio(1);
#pragma unroll
    for (int ks = 0; ks < 4; ++ks) {
      bf16x8 kh = *(const bf16x8*)(B + (ks * 2 + kh2) * 1024);
      bf16x8 kl = *(const bf16x8*)(B + 8192 + (ks * 2 + kh2) * 1024);
      acc = __builtin_amdgcn_mfma_f32_32x32x16_bf16(kh, qh[ks], acc, 0, 0, 0);
      acc = __builtin_amdgcn_mfma_f32_32x32x16_bf16(kh, ql[ks], acc, 0, 0, 0);
      acc = __builtin_amdgcn_mfma_f32_32x32x16_bf16(kl, qh[ks], acc, 0, 0, 0);
    }
    __builtin_amdgcn_s_setprio(0);
    // ---- exp + pack P (A-frag register order; V key axis pre-permuted) ----
    float pr[16];
#pragma unroll
    for (int i = 0; i < 16; ++i) {
      pr[i] = exp2f(acc[i] * 0.18033688011112042f);  // exp(acc/8)
      lsum += pr[i];
    }
    bf16x8 pa[2];
#pragma unroll
    for (int s2 = 0; s2 < 2; ++s2) {
      u32x4 wds;
#pragma unroll
      for (int p2 = 0; p2 < 4; ++p2) {
        unsigned int pk;
        asm("v_cvt_pk_bf16_f32 %0, %1, %2"
            : "=v"(pk)
            : "v"(pr[s2 * 8 + p2 * 2]), "v"(pr[s2 * 8 + p2 * 2 + 1]));
        wds[p2] = pk;
      }
      pa[s2] = __builtin_bit_cast(bf16x8, wds);
    }
    // ---- O += P.V ----
    __builtin_amdgcn_s_setprio(1);
#pragma unroll
    for (int db = 0; db < 2; ++db) {
      bf16x8 v0 = *(const bf16x8*)(B + 16384 + ((kh2 * 2 + 0) * 2 + db) * 1024);
      bf16x8 v1 = *(const bf16x8*)(B + 16384 + ((kh2 * 2 + 1) * 2 + db) * 1024);
      o2[db] = __builtin_amdgcn_mfma_f32_32x32x16_bf16(pa[0], v0, o2[db], 0, 0, 0);
      o2[db] = __builtin_amdgcn_mfma_f32_32x32x16_bf16(pa[1], v1, o2[db], 0, 0, 0);
    }
    __builtin_amdgcn_s_setprio(0);
  };

  // ---- prologue: stage tiles 0,1; certify tile 0 (own 6 outstanding -> 3) ----
  stage(0, 0);
  stage(1, 1);
  asm volatile("s_waitcnt vmcnt(3)" ::: "memory");
  __builtin_amdgcn_s_barrier();

  // ---- main loop: t = 0..29, buffers rotate (t%3), stage t+2, vmcnt(3) ----
#pragma unroll 1
  for (int tb = 0; tb < 30; tb += 3) {
    stage(2, tb + 2);
    compute(0);
    asm volatile("s_waitcnt vmcnt(3) lgkmcnt(0)" ::: "memory");
    __builtin_amdgcn_s_barrier();
    stage(0, tb + 3);
    compute(1);
    asm volatile("s_waitcnt vmcnt(3) lgkmcnt(0)" ::: "memory");
    __builtin_amdgcn_s_barrier();
    stage(1, tb + 4);
    compute(2);
    asm volatile("s_waitcnt vmcnt(3) lgkmcnt(0)" ::: "memory");
    __builtin_amdgcn_s_barrier();
  }
  // ---- tail: t=30 (drain), t=31 ----
  compute(0);
  asm volatile("s_waitcnt vmcnt(0) lgkmcnt(0)" ::: "memory");
  __builtin_amdgcn_s_barrier();
  compute(1);
  __syncthreads();  // all compute reads done before sc overwrites smem

  // ---- epilogue: combine key-halves, normalize, store ----
  float ls = lsum + __shfl_xor(lsum, 32);  // h-pair: full 32-key half-sum per q=l31
  float* sc = (float*)&smem[0][0];
  if (kh2 == 1) {
#pragma unroll
    for (int db = 0; db < 2; ++db)
#pragma unroll
      for (int r = 0; r < 16; ++r)
        sc[(qtile * 2 + db) * 1024 + (h * 16 + r) * 32 + l31] = o2[db][r];
    sc[8192 + qtile * 32 + l31] = ls;
  }
  __syncthreads();
  if (kh2 == 1) return;
  float ltot = ls + sc[8192 + qtile * 32 + l31];
  float inv = 1.0f / ltot;
  sc[8320 + qtile * 32 + l31] = inv;  // broadcast q-indexed -> row-indexed
  asm volatile("s_waitcnt lgkmcnt(0)" ::: "memory");
  float* ob = out + ((size_t)bh * S_LEN + qt * 128 + qtile * 32) * 64;
#pragma unroll
  for (int r = 0; r < 16; ++r) {
    const int qr = (r & 3) + 8 * (r >> 2) + 4 * h;
    float iv = sc[8320 + qtile * 32 + qr];
#pragma unroll
    for (int db = 0; db < 2; ++db) {
      float val = (o2[db][r] + sc[(qtile * 2 + db) * 1024 + (h * 16 + r) * 32 + l31]) * iv;
      ob[(size_t)qr * 64 + db * 32 + l31] = val;
    }
  }
}

extern "C" void kernel_launch(void* const* d_in, const int* in_sizes, int n_in,
                              void* d_out, int out_size, void* d_ws, size_t ws_size,
                              hipStream_t stream) {
  const float* q = (const float*)d_in[0];
  const float* k = (const float*)d_in[1];  // [bh][d][s] (pre-transposed)
  const float* v = (const float*)d_in[2];  // [bh][s][d]
  float* out = (float*)d_out;
  unsigned short* ws = (unsigned short*)d_ws;
  unsigned short* Kh = ws;
  unsigned short* Kl = ws + BH * NN;
  unsigned short* Vh = ws + 2 * BH * NN;
  pack_all<<<dim3(4096), 256, 0, stream>>>(k, v, Kh, Kl, Vh);
  attn_fused<<<dim3(512), 512, 0, stream>>>(q, Kh, Kl, Vh, out);
}